// Round 6
// baseline (631.439 us; speedup 1.0000x reference)
//
#include <hip/hip_runtime.h>
#include <hip/hip_bf16.h>
#include <cstddef>

// Problem constants (B,H,W,C)=(4,96,96,256), G=4, K=3
#define B_   4
#define H_   96
#define W_   96
#define C_   256
#define G_   4
#define CG   64      // C/G
#define NPOS 9       // K*K
#define KC   576     // K*K*CG
#define HW   (H_*W_)      // 9216
#define NPIX (B_*H_*W_)   // 36864

// 2-D pixel tile for the fused kernel
#define TM 4
#define TN 16
#define WR 6          // TM+2
#define WC 18         // TN+2
#define WPOS 108      // WR*WC
#define SWPAD 110     // swin row stride (shorts): odd dword count -> no bank conflict

typedef float f32x4 __attribute__((ext_vector_type(4)));
typedef short bf16x8 __attribute__((ext_vector_type(8)));

static __device__ __forceinline__ ushort f2bf(float f) {
    unsigned u = __float_as_uint(f);
    unsigned r = (u + 0x7fffu + ((u >> 16) & 1u)) >> 16;   // RNE
    return (ushort)r;
}
static __device__ __forceinline__ float bf2f(ushort u) {
    return __uint_as_float(((unsigned)u) << 16);
}

// ---------------------------------------------------------------------------
// K0: transpose w_off [G][3][3][CG][18] -> wt [G][18][9][CG]  (f32)
// ---------------------------------------------------------------------------
__global__ void k_transpose_woff(const float* __restrict__ w_off,
                                 float* __restrict__ wt) {
    int idx = blockIdx.x * 256 + threadIdx.x;
    const int total = G_ * 18 * NPOS * CG;
    if (idx >= total) return;
    int c = idx & 63;
    int r = idx >> 6;
    int nbr = r % NPOS; r /= NPOS;
    int oc  = r % 18;
    int g   = r / 18;
    wt[idx] = w_off[((size_t)(g * NPOS + nbr) * CG + c) * 18 + oc];
}

// ---------------------------------------------------------------------------
// Kc2: w_init [k=256][co=256] -> wT split bf16 [co][k]
// ---------------------------------------------------------------------------
__global__ void k_cvt_wT_split(const float* __restrict__ w_init,
                               ushort* __restrict__ wTh,
                               ushort* __restrict__ wTl) {
    int idx = blockIdx.x * 256 + threadIdx.x;
    if (idx >= 256 * 256) return;
    int co = idx & 255, k = idx >> 8;
    float v = w_init[(size_t)k * 256 + co];
    ushort h = f2bf(v);
    wTh[(size_t)co * 256 + k] = h;
    wTl[(size_t)co * 256 + k] = f2bf(v - bf2f(h));
}

// ---------------------------------------------------------------------------
// Kc3: w_pw [g][k=576][f=64] -> wpwT bf16 (hi only) [g][f][k=576]
// ---------------------------------------------------------------------------
__global__ void k_cvt_wpwT(const float* __restrict__ w_pw,
                           ushort* __restrict__ wpwTh) {
    int idx = blockIdx.x * 256 + threadIdx.x;
    if (idx >= G_ * KC * CG) return;
    int f = idx & 63;
    int k = (idx >> 6) % KC;
    int g = idx / (KC * CG);
    wpwTh[((size_t)g * CG + f) * KC + k] = f2bf(w_pw[((size_t)g * KC + k) * CG + f]);
}

// ---------------------------------------------------------------------------
// K1: init 1x1 conv via split-bf16 MFMA (Ah*Bh + Ah*Bl + Al*Bh ~ f32 exact).
// Reads x in f32 and splits in-kernel (no separate cvt pass for x).
// ---------------------------------------------------------------------------
__global__ void __launch_bounds__(256) k_gemm_init_mfma(
        const float* __restrict__ x,
        const ushort* __restrict__ wTh, const ushort* __restrict__ wTl,
        const float* __restrict__ bias, float* __restrict__ y) {
    __shared__ __align__(16) ushort ath[64][72], atl[64][72];
    __shared__ __align__(16) ushort bth[64][72], btl[64][72];
    int t = threadIdx.x;
    int px0 = blockIdx.x * 64, n0 = blockIdx.y * 64;
    int r = t >> 2, seg = (t & 3) * 16;
    int lane = t & 63, wv = t >> 6;
    int hl = lane & 15, qv = lane >> 4;
    f32x4 acc[4] = {};
    for (int kk = 0; kk < C_; kk += 64) {
        // A: read x f32, split to hi/lo bf16 in-register
        {
            const float4* xs = (const float4*)(x + (size_t)(px0 + r) * C_ + kk + seg);
            ushort hbuf[16], lbuf[16];
            #pragma unroll
            for (int j = 0; j < 4; j++) {
                float4 v = xs[j];
                float vv[4] = {v.x, v.y, v.z, v.w};
                #pragma unroll
                for (int e2 = 0; e2 < 4; e2++) {
                    ushort h = f2bf(vv[e2]);
                    hbuf[j * 4 + e2] = h;
                    lbuf[j * 4 + e2] = f2bf(vv[e2] - bf2f(h));
                }
            }
            *(uint4*)&ath[r][seg]     = *(uint4*)&hbuf[0];
            *(uint4*)&ath[r][seg + 8] = *(uint4*)&hbuf[8];
            *(uint4*)&atl[r][seg]     = *(uint4*)&lbuf[0];
            *(uint4*)&atl[r][seg + 8] = *(uint4*)&lbuf[8];
        }
        // B: already split in global
        {
            size_t woff = (size_t)(n0 + r) * C_ + kk + seg;
            const uint4* qh = (const uint4*)(wTh + woff);
            const uint4* ql = (const uint4*)(wTl + woff);
            uint4 c0 = qh[0], c1 = qh[1], d0 = ql[0], d1 = ql[1];
            *(uint4*)&bth[r][seg] = c0; *(uint4*)&bth[r][seg + 8] = c1;
            *(uint4*)&btl[r][seg] = d0; *(uint4*)&btl[r][seg + 8] = d1;
        }
        __syncthreads();
        #pragma unroll
        for (int ks = 0; ks < 2; ks++) {
            bf16x8 ah_ = *(const bf16x8*)&ath[wv * 16 + hl][ks * 32 + qv * 8];
            bf16x8 al_ = *(const bf16x8*)&atl[wv * 16 + hl][ks * 32 + qv * 8];
            #pragma unroll
            for (int cg = 0; cg < 4; cg++) {
                bf16x8 bh_ = *(const bf16x8*)&bth[cg * 16 + hl][ks * 32 + qv * 8];
                bf16x8 bl_ = *(const bf16x8*)&btl[cg * 16 + hl][ks * 32 + qv * 8];
                acc[cg] = __builtin_amdgcn_mfma_f32_16x16x32_bf16(ah_, bh_, acc[cg], 0, 0, 0);
                acc[cg] = __builtin_amdgcn_mfma_f32_16x16x32_bf16(ah_, bl_, acc[cg], 0, 0, 0);
                acc[cg] = __builtin_amdgcn_mfma_f32_16x16x32_bf16(al_, bh_, acc[cg], 0, 0, 0);
            }
        }
        __syncthreads();
    }
    #pragma unroll
    for (int cg = 0; cg < 4; cg++) {
        int col = n0 + cg * 16 + hl;
        float bb = bias[col];
        #pragma unroll
        for (int rg = 0; rg < 4; rg++) {
            int row = px0 + wv * 16 + qv * 4 + rg;
            y[(size_t)row * C_ + col] = acc[cg][rg] + bb;
        }
    }
}

// ---------------------------------------------------------------------------
// K2: offsets 3x3 conv (64 -> 18), ALL groups (blockIdx.y = g).  (f32)
// ---------------------------------------------------------------------------
__global__ void __launch_bounds__(256) k_offconv_all(
        const float* __restrict__ y, const float* __restrict__ wt,
        const float* __restrict__ b_off, float* __restrict__ off_all) {
    int g = blockIdx.y;
    const float* wt_g = wt + (size_t)g * 18 * NPOS * CG;
    __shared__ float ws_[18 * NPOS * CG];
    for (int i = threadIdx.x; i < 18 * NPOS * CG; i += 256) ws_[i] = wt_g[i];
    __syncthreads();
    int lane = threadIdx.x & 63;
    float bo = b_off[g * 18 + (lane < 18 ? lane : 0)];
    int wv = blockIdx.x * 4 + (threadIdx.x >> 6);
    for (int px = wv; px < NPIX; px += 4096) {
        int b = px / HW; int rem = px - b * HW;
        int yy = rem / W_; int xx = rem - yy * W_;
        float partial[18];
        #pragma unroll
        for (int oc = 0; oc < 18; oc++) partial[oc] = 0.f;
        const float* yb = y + (size_t)b * HW * C_ + g * CG + lane;
        for (int di = 0; di < 3; di++) {
            int ny = yy + di - 1; if ((unsigned)ny >= H_) continue;
            for (int dj = 0; dj < 3; dj++) {
                int nx = xx + dj - 1; if ((unsigned)nx >= W_) continue;
                float yv = yb[(size_t)(ny * W_ + nx) * C_];
                int nbr = di * 3 + dj;
                #pragma unroll
                for (int oc = 0; oc < 18; oc++)
                    partial[oc] += yv * ws_[(oc * NPOS + nbr) * CG + lane];
            }
        }
        float res = 0.f;
        #pragma unroll
        for (int oc = 0; oc < 18; oc++) {
            float v = partial[oc];
            #pragma unroll
            for (int s = 32; s >= 1; s >>= 1) v += __shfl_xor(v, s, 64);
            if (lane == oc) res = v;
        }
        if (lane < 18) off_all[((size_t)g * NPIX + px) * 18 + lane] = res + bo;
    }
}

// ---------------------------------------------------------------------------
// K3: precompute bilinear weights + gather indices per (g, px, p).
// ---------------------------------------------------------------------------
__global__ void __launch_bounds__(256) k_prep(
        const float* __restrict__ off_all, float* __restrict__ tab) {
    int tid = blockIdx.x * 256 + threadIdx.x;
    const int total = G_ * NPIX * NPOS;
    if (tid >= total) return;
    int p = tid % NPOS; int rem = tid / NPOS;
    int px = rem % NPIX; int g = rem / NPIX;
    int b = px / HW; int r2 = px - b * HW;
    int yy = r2 / W_; int xx = r2 - yy * W_;
    float ox = off_all[(size_t)rem * 18 + 2 * p];
    float oy = off_all[(size_t)rem * 18 + 2 * p + 1];
    int di = p / 3, dj = p - di * 3;
    float lx = (float)(xx + dj - 1) + ox;
    float ly = (float)(yy + di - 1) + oy;
    lx = fminf(fmaxf(lx, 0.f), (float)(W_ - 1));
    ly = fminf(fmaxf(ly, 0.f), (float)(H_ - 1));
    float x0f = floorf(lx), y0f = floorf(ly);
    float x1f = fminf(x0f + 1.f, (float)(W_ - 1));
    float y1f = fminf(y0f + 1.f, (float)(H_ - 1));
    float wa = (x1f - lx) * (y1f - ly);
    float wb = (x1f - lx) * (ly - y0f);
    float wc = (lx - x0f) * (y1f - ly);
    float wd = (lx - x0f) * (ly - y0f);
    int ix0 = (int)x0f, iy0 = (int)y0f, ix1 = (int)x1f, iy1 = (int)y1f;
    int base = b * HW * C_ + g * CG;
    int ia = base + (iy0 * W_ + ix0) * C_;
    int ib = base + (iy1 * W_ + ix0) * C_;
    int ic = base + (iy0 * W_ + ix1) * C_;
    int id = base + (iy1 * W_ + ix1) * C_;
    float* tp8 = tab + (size_t)tid * 8;
    *(float4*)tp8 = make_float4(wa, wb, wc, wd);
    int4 iv = make_int4(ia, ib, ic, id);
    *(float4*)(tp8 + 4) = *(float4*)&iv;
}

// ---------------------------------------------------------------------------
// K4: fused sample + depthwise-3x3 + bf16-MFMA pointwise, ALL groups.
// swin is [ch][pos] (stride 110 shorts = 55 dwords, odd -> conflict-free).
// Sampling: each wave handles a pos-PAIR per iter (lane = ch): tab entries
// wave-uniform (scalarizable), 8 coalesced gathers, one ushort2 LDS write.
// Depthwise: ushort2 run reads + register sliding, branch-free.
// Pointwise: single-bf16 MFMA (h and w_pw hi only; y stays exact upstream,
// protecting the sensitive offsets path).
// ---------------------------------------------------------------------------
__global__ void __launch_bounds__(256, 5) k_dwpw_all(
        const float* __restrict__ y, const float* __restrict__ tab,
        const float* __restrict__ w_dw, const float* __restrict__ b_dw,
        const ushort* __restrict__ wpwTh, const float* __restrict__ b_pw,
        float* __restrict__ out) {
    __shared__ __align__(16) ushort swin[64][SWPAD];  // 13.75 KB [ch][pos]
    __shared__ __align__(16) ushort ht [64][72];      //  9.0 KB
    __shared__ __align__(16) ushort wt_[64][72];      //  9.0 KB
    int g = blockIdx.y;
    int tile = blockIdx.x;              // b*144 + tr*6 + tc
    int b = tile / 144; int trem = tile - b * 144;
    int r0 = (trem / 6) * TM;
    int c0 = (trem - (trem / 6) * 6) * TN;
    int t = threadIdx.x;
    int lane = t & 63, wv = t >> 6;
    int hl = lane & 15, qv = lane >> 4;
    int rr = t >> 2, seg = (t & 3) * 16;
    const float* wdwg = w_dw + (size_t)g * NPOS * KC;
    const float* bdwg = b_dw + (size_t)g * KC;
    const ushort* wpwg = wpwTh + (size_t)g * CG * KC;
    const float* bpwg = b_pw + (size_t)g * CG;
    const float* tabg = tab + (size_t)g * NPIX * NPOS * 8;
    const int bHW = b * HW;

    f32x4 acc[4] = {};
    for (int p = 0; p < NPOS; p++) {
        // stage pointwise-W chunk (hi only): wt_[f][k0..64)
        {
            const uint4* s0 = (const uint4*)(wpwg + (size_t)rr * KC + p * 64 + seg);
            uint4 w0 = s0[0], w1 = s0[1];
            *(uint4*)&wt_[rr][seg]     = w0;
            *(uint4*)&wt_[rr][seg + 8] = w1;
        }
        // sample the 6x18 window, pos-pair per wave-iteration
        for (int q = wv; q < 54; q += 4) {
            int wr  = q / 9;
            int wc0 = (q - wr * 9) * 2;          // even, <= 16 (no row wrap)
            int ny  = r0 - 1 + wr;
            int nx0 = c0 - 1 + wc0;
            int nyc  = min(max(ny, 0), H_ - 1);
            int nxc0 = min(max(nx0, 0), W_ - 1);
            int nxc1 = min(nx0 + 1, W_ - 1);     // nx0+1 >= 0 always
            bool okr = (unsigned)ny < (unsigned)H_;
            bool in0 = okr && ((unsigned)nx0 < (unsigned)W_);
            bool in1 = okr && ((unsigned)(nx0 + 1) < (unsigned)W_);
            int npx0 = bHW + nyc * W_ + nxc0;
            int npx1 = bHW + nyc * W_ + nxc1;
            const float* e0 = tabg + ((size_t)npx0 * NPOS + p) * 8;
            const float* e1 = tabg + ((size_t)npx1 * NPOS + p) * 8;
            float4 wA = *(const float4*)e0;
            const int* eiA = (const int*)(e0 + 4);
            float4 wB = *(const float4*)e1;
            const int* eiB = (const int*)(e1 + 4);
            float s0v = wA.x * y[eiA[0] + lane] + wA.y * y[eiA[1] + lane]
                      + wA.z * y[eiA[2] + lane] + wA.w * y[eiA[3] + lane];
            float s1v = wB.x * y[eiB[0] + lane] + wB.y * y[eiB[1] + lane]
                      + wB.z * y[eiB[2] + lane] + wB.w * y[eiB[3] + lane];
            ushort2 pr;
            pr.x = f2bf(in0 ? s0v : 0.f);
            pr.y = f2bf(in1 ? s1v : 0.f);
            *(ushort2*)&swin[lane][2 * q] = pr;
        }
        __syncthreads();
        // depthwise combine (register sliding, ushort2 reads) -> ht (bf16)
        int o = p * 64 + lane;
        float wd9[9];
        #pragma unroll
        for (int tap = 0; tap < 9; tap++) wd9[tap] = wdwg[tap * KC + o];
        float bd = bdwg[o];
        float2 aa0, aa1, aa2;
        {
            ushort2 v0 = *(const ushort2*)&swin[lane][(wv + 0) * WC];
            ushort2 v1 = *(const ushort2*)&swin[lane][(wv + 1) * WC];
            ushort2 v2 = *(const ushort2*)&swin[lane][(wv + 2) * WC];
            aa0 = make_float2(bf2f(v0.x), bf2f(v0.y));
            aa1 = make_float2(bf2f(v1.x), bf2f(v1.y));
            aa2 = make_float2(bf2f(v2.x), bf2f(v2.y));
        }
        #pragma unroll
        for (int pc = 0; pc < TN; pc += 2) {
            ushort2 v0 = *(const ushort2*)&swin[lane][(wv + 0) * WC + pc + 2];
            ushort2 v1 = *(const ushort2*)&swin[lane][(wv + 1) * WC + pc + 2];
            ushort2 v2 = *(const ushort2*)&swin[lane][(wv + 2) * WC + pc + 2];
            float2 bb0 = make_float2(bf2f(v0.x), bf2f(v0.y));
            float2 bb1 = make_float2(bf2f(v1.x), bf2f(v1.y));
            float2 bb2 = make_float2(bf2f(v2.x), bf2f(v2.y));
            float h0 = bd
                + aa0.x * wd9[0] + aa0.y * wd9[1] + bb0.x * wd9[2]
                + aa1.x * wd9[3] + aa1.y * wd9[4] + bb1.x * wd9[5]
                + aa2.x * wd9[6] + aa2.y * wd9[7] + bb2.x * wd9[8];
            float h1 = bd
                + aa0.y * wd9[0] + bb0.x * wd9[1] + bb0.y * wd9[2]
                + aa1.y * wd9[3] + bb1.x * wd9[4] + bb1.y * wd9[5]
                + aa2.y * wd9[6] + bb2.x * wd9[7] + bb2.y * wd9[8];
            ht[wv * 16 + pc][lane]     = f2bf(h0);
            ht[wv * 16 + pc + 1][lane] = f2bf(h1);
            aa0 = bb0; aa1 = bb1; aa2 = bb2;
        }
        __syncthreads();
        // pointwise GEMM chunk via MFMA (hi only)
        #pragma unroll
        for (int ks = 0; ks < 2; ks++) {
            bf16x8 a = *(const bf16x8*)&ht[wv * 16 + hl][ks * 32 + qv * 8];
            #pragma unroll
            for (int cg = 0; cg < 4; cg++) {
                bf16x8 bfr = *(const bf16x8*)&wt_[cg * 16 + hl][ks * 32 + qv * 8];
                acc[cg] = __builtin_amdgcn_mfma_f32_16x16x32_bf16(a, bfr, acc[cg], 0, 0, 0);
            }
        }
        __syncthreads();
    }
    // epilogue: D row = qv*4+rg -> pixel col; wave wv -> pixel row r0+wv
    #pragma unroll
    for (int cg = 0; cg < 4; cg++) {
        int col = cg * 16 + hl;
        float bb = bpwg[col];
        #pragma unroll
        for (int rg = 0; rg < 4; rg++) {
            int pcol = qv * 4 + rg;
            int px = bHW + (r0 + wv) * W_ + (c0 + pcol);
            out[(size_t)px * C_ + g * CG + col] = acc[cg][rg] + bb;
        }
    }
}

// ---------------------------------------------------------------------------
// ws layout: y 37.7MB | wt 166KB | off_all 10.6MB | tab 42.5MB |
//            wTh/wTl 128KB each | wpwTh 288KB    (~91 MB total)
// ---------------------------------------------------------------------------
extern "C" void kernel_launch(void* const* d_in, const int* in_sizes, int n_in,
                              void* d_out, int out_size, void* d_ws, size_t ws_size,
                              hipStream_t stream) {
    const float* x      = (const float*)d_in[0];
    const float* w_init = (const float*)d_in[1];
    const float* b_init = (const float*)d_in[2];
    const float* w_off  = (const float*)d_in[3];
    const float* b_off  = (const float*)d_in[4];
    const float* w_dw   = (const float*)d_in[5];
    const float* b_dw   = (const float*)d_in[6];
    const float* w_pw   = (const float*)d_in[7];
    const float* b_pw   = (const float*)d_in[8];
    float* out = (float*)d_out;

    float* y       = (float*)d_ws;
    float* wt      = y       + (size_t)NPIX * C_;
    float* off_all = wt      + (size_t)G_ * 18 * NPOS * CG;
    float* tab     = off_all + (size_t)G_ * NPIX * 18;
    ushort* wTh    = (ushort*)(tab + (size_t)G_ * NPIX * NPOS * 8);
    ushort* wTl    = wTh + 256 * 256;
    ushort* wpwTh  = wTl + 256 * 256;

    k_transpose_woff<<<(G_ * 18 * NPOS * CG + 255) / 256, 256, 0, stream>>>(w_off, wt);
    k_cvt_wT_split<<<(256 * 256 + 255) / 256, 256, 0, stream>>>(w_init, wTh, wTl);
    k_cvt_wpwT<<<(G_ * KC * CG + 255) / 256, 256, 0, stream>>>(w_pw, wpwTh);
    k_gemm_init_mfma<<<dim3(NPIX / 64, C_ / 64), 256, 0, stream>>>(x, wTh, wTl, b_init, y);
    k_offconv_all<<<dim3(1024, G_), 256, 0, stream>>>(y, wt, b_off, off_all);
    k_prep<<<(G_ * NPIX * NPOS + 255) / 256, 256, 0, stream>>>(off_all, tab);
    k_dwpw_all<<<dim3(576, G_), 256, 0, stream>>>(y, tab, w_dw, b_dw,
                                                  wpwTh, b_pw, out);
}

// Round 8
// 519.313 us; speedup vs baseline: 1.2159x; 1.2159x over previous
//
#include <hip/hip_runtime.h>
#include <hip/hip_bf16.h>
#include <cstddef>

// Problem constants (B,H,W,C)=(4,96,96,256), G=4, K=3
#define B_   4
#define H_   96
#define W_   96
#define C_   256
#define G_   4
#define CG   64      // C/G
#define NPOS 9       // K*K
#define KC   576     // K*K*CG
#define HW   (H_*W_)      // 9216
#define NPIX (B_*H_*W_)   // 36864

// 2-D pixel tile for the fused kernel
#define TM 4
#define TN 16
#define WROWS 6       // TM+2
#define WCOLS 18      // TN+2
#define WPOS  108     // WROWS*WCOLS

typedef float f32x4 __attribute__((ext_vector_type(4)));
typedef float f32x2 __attribute__((ext_vector_type(2)));
typedef short bf16x8 __attribute__((ext_vector_type(8)));

static __device__ __forceinline__ ushort f2bf(float f) {
    unsigned u = __float_as_uint(f);
    unsigned r = (u + 0x7fffu + ((u >> 16) & 1u)) >> 16;   // RNE
    return (ushort)r;
}
static __device__ __forceinline__ float bf2f(ushort u) {
    return __uint_as_float(((unsigned)u) << 16);
}
// unpack uint holding (ch_lo, ch_hi) bf16 pair -> float2
static __device__ __forceinline__ f32x2 up2(unsigned u) {
    f32x2 f;
    f.x = __uint_as_float(u << 16);
    f.y = __uint_as_float(u & 0xFFFF0000u);
    return f;
}

// ---------------------------------------------------------------------------
// K0: transpose w_off [G][3][3][CG][18] -> wt [G][18][9][CG]  (f32)
// ---------------------------------------------------------------------------
__global__ void k_transpose_woff(const float* __restrict__ w_off,
                                 float* __restrict__ wt) {
    int idx = blockIdx.x * 256 + threadIdx.x;
    const int total = G_ * 18 * NPOS * CG;
    if (idx >= total) return;
    int c = idx & 63;
    int r = idx >> 6;
    int nbr = r % NPOS; r /= NPOS;
    int oc  = r % 18;
    int g   = r / 18;
    wt[idx] = w_off[((size_t)(g * NPOS + nbr) * CG + c) * 18 + oc];
}

// ---------------------------------------------------------------------------
// Kc2: w_init [k=256][co=256] -> wT split bf16 [co][k]
// ---------------------------------------------------------------------------
__global__ void k_cvt_wT_split(const float* __restrict__ w_init,
                               ushort* __restrict__ wTh,
                               ushort* __restrict__ wTl) {
    int idx = blockIdx.x * 256 + threadIdx.x;
    if (idx >= 256 * 256) return;
    int co = idx & 255, k = idx >> 8;
    float v = w_init[(size_t)k * 256 + co];
    ushort h = f2bf(v);
    wTh[(size_t)co * 256 + k] = h;
    wTl[(size_t)co * 256 + k] = f2bf(v - bf2f(h));
}

// ---------------------------------------------------------------------------
// Kc3: w_pw [g][k=576][f=64] -> wpwT bf16 (hi only) [g][f][k=576]
// ---------------------------------------------------------------------------
__global__ void k_cvt_wpwT(const float* __restrict__ w_pw,
                           ushort* __restrict__ wpwTh) {
    int idx = blockIdx.x * 256 + threadIdx.x;
    if (idx >= G_ * KC * CG) return;
    int f = idx & 63;
    int k = (idx >> 6) % KC;
    int g = idx / (KC * CG);
    wpwTh[((size_t)g * CG + f) * KC + k] = f2bf(w_pw[((size_t)g * KC + k) * CG + f]);
}

// ---------------------------------------------------------------------------
// K1: init 1x1 conv via split-bf16 MFMA (~f32 exact).
// Writes y (f32, exact - feeds the discontinuity-sensitive offsets path)
// AND yb (bf16 copy - feeds the smooth gather-value path).
// ---------------------------------------------------------------------------
__global__ void __launch_bounds__(256) k_gemm_init_mfma(
        const float* __restrict__ x,
        const ushort* __restrict__ wTh, const ushort* __restrict__ wTl,
        const float* __restrict__ bias, float* __restrict__ y,
        ushort* __restrict__ yb) {
    __shared__ __align__(16) ushort ath[64][72], atl[64][72];
    __shared__ __align__(16) ushort bth[64][72], btl[64][72];
    int t = threadIdx.x;
    int px0 = blockIdx.x * 64, n0 = blockIdx.y * 64;
    int r = t >> 2, seg = (t & 3) * 16;
    int lane = t & 63, wv = t >> 6;
    int hl = lane & 15, qv = lane >> 4;
    f32x4 acc[4] = {};
    for (int kk = 0; kk < C_; kk += 64) {
        {
            const float4* xs = (const float4*)(x + (size_t)(px0 + r) * C_ + kk + seg);
            ushort hbuf[16], lbuf[16];
            #pragma unroll
            for (int j = 0; j < 4; j++) {
                float4 v = xs[j];
                float vv[4] = {v.x, v.y, v.z, v.w};
                #pragma unroll
                for (int e2 = 0; e2 < 4; e2++) {
                    ushort h = f2bf(vv[e2]);
                    hbuf[j * 4 + e2] = h;
                    lbuf[j * 4 + e2] = f2bf(vv[e2] - bf2f(h));
                }
            }
            *(uint4*)&ath[r][seg]     = *(uint4*)&hbuf[0];
            *(uint4*)&ath[r][seg + 8] = *(uint4*)&hbuf[8];
            *(uint4*)&atl[r][seg]     = *(uint4*)&lbuf[0];
            *(uint4*)&atl[r][seg + 8] = *(uint4*)&lbuf[8];
        }
        {
            size_t woff = (size_t)(n0 + r) * C_ + kk + seg;
            const uint4* qh = (const uint4*)(wTh + woff);
            const uint4* ql = (const uint4*)(wTl + woff);
            uint4 c0 = qh[0], c1 = qh[1], d0 = ql[0], d1 = ql[1];
            *(uint4*)&bth[r][seg] = c0; *(uint4*)&bth[r][seg + 8] = c1;
            *(uint4*)&btl[r][seg] = d0; *(uint4*)&btl[r][seg + 8] = d1;
        }
        __syncthreads();
        #pragma unroll
        for (int ks = 0; ks < 2; ks++) {
            bf16x8 ah_ = *(const bf16x8*)&ath[wv * 16 + hl][ks * 32 + qv * 8];
            bf16x8 al_ = *(const bf16x8*)&atl[wv * 16 + hl][ks * 32 + qv * 8];
            #pragma unroll
            for (int cg = 0; cg < 4; cg++) {
                bf16x8 bh_ = *(const bf16x8*)&bth[cg * 16 + hl][ks * 32 + qv * 8];
                bf16x8 bl_ = *(const bf16x8*)&btl[cg * 16 + hl][ks * 32 + qv * 8];
                acc[cg] = __builtin_amdgcn_mfma_f32_16x16x32_bf16(ah_, bh_, acc[cg], 0, 0, 0);
                acc[cg] = __builtin_amdgcn_mfma_f32_16x16x32_bf16(ah_, bl_, acc[cg], 0, 0, 0);
                acc[cg] = __builtin_amdgcn_mfma_f32_16x16x32_bf16(al_, bh_, acc[cg], 0, 0, 0);
            }
        }
        __syncthreads();
    }
    #pragma unroll
    for (int cg = 0; cg < 4; cg++) {
        int col = n0 + cg * 16 + hl;
        float bb = bias[col];
        #pragma unroll
        for (int rg = 0; rg < 4; rg++) {
            int row = px0 + wv * 16 + qv * 4 + rg;
            float v = acc[cg][rg] + bb;
            y [(size_t)row * C_ + col] = v;
            yb[(size_t)row * C_ + col] = f2bf(v);
        }
    }
}

// ---------------------------------------------------------------------------
// K2: offsets 3x3 conv (64 -> 18), ALL groups (blockIdx.y = g). f32 exact.
// ---------------------------------------------------------------------------
__global__ void __launch_bounds__(256) k_offconv_all(
        const float* __restrict__ y, const float* __restrict__ wt,
        const float* __restrict__ b_off, float* __restrict__ off_all) {
    int g = blockIdx.y;
    const float* wt_g = wt + (size_t)g * 18 * NPOS * CG;
    __shared__ float ws_[18 * NPOS * CG];
    for (int i = threadIdx.x; i < 18 * NPOS * CG; i += 256) ws_[i] = wt_g[i];
    __syncthreads();
    int lane = threadIdx.x & 63;
    float bo = b_off[g * 18 + (lane < 18 ? lane : 0)];
    int wv = blockIdx.x * 4 + (threadIdx.x >> 6);
    for (int px = wv; px < NPIX; px += 4096) {
        int b = px / HW; int rem = px - b * HW;
        int yy = rem / W_; int xx = rem - yy * W_;
        float partial[18];
        #pragma unroll
        for (int oc = 0; oc < 18; oc++) partial[oc] = 0.f;
        const float* yb_ = y + (size_t)b * HW * C_ + g * CG + lane;
        for (int di = 0; di < 3; di++) {
            int ny = yy + di - 1; if ((unsigned)ny >= H_) continue;
            for (int dj = 0; dj < 3; dj++) {
                int nx = xx + dj - 1; if ((unsigned)nx >= W_) continue;
                float yv = yb_[(size_t)(ny * W_ + nx) * C_];
                int nbr = di * 3 + dj;
                #pragma unroll
                for (int oc = 0; oc < 18; oc++)
                    partial[oc] += yv * ws_[(oc * NPOS + nbr) * CG + lane];
            }
        }
        float res = 0.f;
        #pragma unroll
        for (int oc = 0; oc < 18; oc++) {
            float v = partial[oc];
            #pragma unroll
            for (int s = 32; s >= 1; s >>= 1) v += __shfl_xor(v, s, 64);
            if (lane == oc) res = v;
        }
        if (lane < 18) off_all[((size_t)g * NPIX + px) * 18 + lane] = res + bo;
    }
}

// ---------------------------------------------------------------------------
// K3: sampling (per pass). Each wave: 4 samples (same p, consecutive px),
// processed as 2 pairs; half-wave = one sample, lane = ch-pair -> every
// gather/store is a full 256B transaction. Offsets math f32 == reference.
// Writes smp[gi][p][px][64ch] bf16.
// ---------------------------------------------------------------------------
__global__ void __launch_bounds__(256) k_sample(
        const ushort* __restrict__ yb, const float* __restrict__ off_all,
        ushort* __restrict__ smp, int g0) {
    int gi = blockIdx.y;
    int g = g0 + gi;
    int t = threadIdx.x;
    int lane = t & 63, wv = t >> 6;
    int hs = lane >> 5;          // half-wave = sample select
    int cl = lane & 31;          // ch-pair index
    int w = blockIdx.x * 4 + wv;
    int s0 = w * 4;
    int p   = s0 / NPIX;         // wave-uniform (NPIX % 4 == 0)
    int px0 = s0 - p * NPIX;
    int di = p / 3, dj = p - di * 3;
    const float* offg = off_all + (size_t)g * NPIX * 18;
    const unsigned* ybu = (const unsigned*)yb;     // [pix][128] uint (2ch each)
    unsigned* smpg = (unsigned*)smp + (size_t)gi * NPOS * NPIX * 32;
    #pragma unroll
    for (int q = 0; q < 2; q++) {
        int px = px0 + 2 * q + hs;
        float2 o2 = *(const float2*)&offg[(size_t)px * 18 + 2 * p];
        int b = px / HW; int r2 = px - b * HW;
        int yy = r2 / W_; int xx = r2 - yy * W_;
        float lx = (float)(xx + dj - 1) + o2.x;
        float ly = (float)(yy + di - 1) + o2.y;
        lx = fminf(fmaxf(lx, 0.f), (float)(W_ - 1));
        ly = fminf(fmaxf(ly, 0.f), (float)(H_ - 1));
        float x0f = floorf(lx), y0f = floorf(ly);
        float x1f = fminf(x0f + 1.f, (float)(W_ - 1));
        float y1f = fminf(y0f + 1.f, (float)(H_ - 1));
        float wa = (x1f - lx) * (y1f - ly);
        float wb = (x1f - lx) * (ly - y0f);
        float wc = (lx - x0f) * (y1f - ly);
        float wd = (lx - x0f) * (ly - y0f);
        int ix0 = (int)x0f, iy0 = (int)y0f, ix1 = (int)x1f, iy1 = (int)y1f;
        const unsigned* base = ybu + ((size_t)b * HW) * 128 + g * 32 + cl;
        f32x2 Ia = up2(base[(iy0 * W_ + ix0) * 128]);
        f32x2 Ib = up2(base[(iy1 * W_ + ix0) * 128]);
        f32x2 Ic = up2(base[(iy0 * W_ + ix1) * 128]);
        f32x2 Id = up2(base[(iy1 * W_ + ix1) * 128]);
        f32x2 v = wa * Ia + wb * Ib + wc * Ic + wd * Id;
        unsigned packed = (unsigned)f2bf(v.x) | ((unsigned)f2bf(v.y) << 16);
        smpg[((size_t)p * NPIX + px) * 32 + cl] = packed;
    }
}

// ---------------------------------------------------------------------------
// K4: window-stage + depthwise-3x3 + bf16-MFMA pointwise (per pass).
// Staging: window rows are 18 CONTIGUOUS pixels in smp -> uint2 bulk copy
// (7 loads/thread/chunk), OOB entries zeroed at stage time.
// Depthwise: thread = (ch-pair, 8px), float2 math, sliding window.
// ---------------------------------------------------------------------------
__global__ void __launch_bounds__(256, 4) k_dwpw(
        const ushort* __restrict__ smp,
        const float* __restrict__ w_dw, const float* __restrict__ b_dw,
        const ushort* __restrict__ wpwTh, const float* __restrict__ b_pw,
        float* __restrict__ out, int g0) {
    __shared__ __align__(16) ushort swin[WPOS][64];   // 13.5 KB [pos][ch]
    __shared__ __align__(16) ushort ht [64][72];      //  9.0 KB
    __shared__ __align__(16) ushort wt_[64][72];      //  9.0 KB
    int gi = blockIdx.y;
    int g = g0 + gi;
    int tile = blockIdx.x;              // b*144 + tr*6 + tc
    int b = tile / 144; int trem = tile - b * 144;
    int r0 = (trem / 6) * TM;
    int c0 = (trem - (trem / 6) * 6) * TN;
    int t = threadIdx.x;
    int lane = t & 63, wv = t >> 6;
    int hl = lane & 15, qv = lane >> 4;
    int rr = t >> 2, seg = (t & 3) * 16;
    const float* wdwg = w_dw + (size_t)g * NPOS * KC;
    const float* bdwg = b_dw + (size_t)g * KC;
    const ushort* wpwg = wpwTh + (size_t)g * CG * KC;
    const float* bpwg = b_pw + (size_t)g * CG;
    const int bHW = b * HW;
    // dw thread mapping
    int cp  = t & 31;          // channels 2cp, 2cp+1
    int pxg = t >> 5;          // 0..7
    int pr  = pxg >> 1;        // tile row 0..3
    int ph  = pxg & 1;         // col half 0..1

    f32x4 acc[4] = {};
    for (int p = 0; p < NPOS; p++) {
        // stage pointwise-W chunk: wt_[f][k0..64)
        {
            const uint4* s0 = (const uint4*)(wpwg + (size_t)rr * KC + p * 64 + seg);
            uint4 w0 = s0[0], w1 = s0[1];
            *(uint4*)&wt_[rr][seg]     = w0;
            *(uint4*)&wt_[rr][seg + 8] = w1;
        }
        // stage sample window: 6 rows x 18 px x 64ch = 1728 uint2
        const ushort* smp_p = smp + (size_t)(gi * NPOS + p) * NPIX * 64;
        #pragma unroll
        for (int k = 0; k < 7; k++) {
            int i = t + k * 256;
            if (i < 1728) {
                int wr  = i / 288;         // 288 uint2 per window row
                int rem = i - wr * 288;
                int pxr = rem >> 4;        // 0..17
                int cq  = rem & 15;        // x4 ch
                int ny = r0 - 1 + wr, nx = c0 - 1 + pxr;
                bool inb = ((unsigned)ny < (unsigned)H_) && ((unsigned)nx < (unsigned)W_);
                uint2 v = make_uint2(0u, 0u);
                if (inb)
                    v = *(const uint2*)(smp_p + ((size_t)(bHW + ny * W_ + nx)) * 64 + cq * 4);
                *(uint2*)&swin[wr * WCOLS + pxr][cq * 4] = v;
            }
        }
        __syncthreads();
        // depthwise combine: thread = (ch-pair cp, 8 px), float2 math
        {
            f32x2 wd2[9];
            #pragma unroll
            for (int tap = 0; tap < 9; tap++) {
                float2 wv2 = *(const float2*)&wdwg[tap * KC + p * 64 + 2 * cp];
                wd2[tap] = {wv2.x, wv2.y};
            }
            float2 bdv = *(const float2*)&bdwg[p * 64 + 2 * cp];
            int rb0 = (pr + 0) * WCOLS + ph * 8;
            int rb1 = (pr + 1) * WCOLS + ph * 8;
            int rb2 = (pr + 2) * WCOLS + ph * 8;
            #define RD2(pos) up2(*(const unsigned*)&swin[pos][2 * cp])
            f32x2 a0 = RD2(rb0), e0 = RD2(rb0 + 1);
            f32x2 a1 = RD2(rb1), e1 = RD2(rb1 + 1);
            f32x2 a2 = RD2(rb2), e2 = RD2(rb2 + 1);
            #pragma unroll
            for (int c = 0; c < 8; c++) {
                f32x2 c0v = RD2(rb0 + c + 2);
                f32x2 c1v = RD2(rb1 + c + 2);
                f32x2 c2v = RD2(rb2 + c + 2);
                f32x2 hv = {bdv.x, bdv.y};
                hv = hv + a0 * wd2[0] + e0 * wd2[1] + c0v * wd2[2]
                        + a1 * wd2[3] + e1 * wd2[4] + c1v * wd2[5]
                        + a2 * wd2[6] + e2 * wd2[7] + c2v * wd2[8];
                int pxl = pr * 16 + ph * 8 + c;
                unsigned up = (unsigned)f2bf(hv.x) | ((unsigned)f2bf(hv.y) << 16);
                *(unsigned*)&ht[pxl][2 * cp] = up;
                a0 = e0; e0 = c0v; a1 = e1; e1 = c1v; a2 = e2; e2 = c2v;
            }
            #undef RD2
        }
        __syncthreads();
        // pointwise GEMM chunk via MFMA
        #pragma unroll
        for (int ks = 0; ks < 2; ks++) {
            bf16x8 a = *(const bf16x8*)&ht[wv * 16 + hl][ks * 32 + qv * 8];
            #pragma unroll
            for (int cg = 0; cg < 4; cg++) {
                bf16x8 bfr = *(const bf16x8*)&wt_[cg * 16 + hl][ks * 32 + qv * 8];
                acc[cg] = __builtin_amdgcn_mfma_f32_16x16x32_bf16(a, bfr, acc[cg], 0, 0, 0);
            }
        }
        __syncthreads();
    }
    // epilogue
    #pragma unroll
    for (int cg = 0; cg < 4; cg++) {
        int col = cg * 16 + hl;
        float bb = bpwg[col];
        #pragma unroll
        for (int rg = 0; rg < 4; rg++) {
            int pcol = qv * 4 + rg;
            int px = bHW + (r0 + wv) * W_ + (c0 + pcol);
            out[(size_t)px * C_ + g * CG + col] = acc[cg][rg] + bb;
        }
    }
}

// ---------------------------------------------------------------------------
// ws layout: wt 166KB | off_all 10.6MB | y(f32) 37.7MB | yb(bf16) 18.9MB |
//            wTh/wTl 128KB each | wpwTh 288KB | smp ng*42.5MB
// ng (groups/pass) chosen at runtime from ws_size (deterministic).
// ---------------------------------------------------------------------------
extern "C" void kernel_launch(void* const* d_in, const int* in_sizes, int n_in,
                              void* d_out, int out_size, void* d_ws, size_t ws_size,
                              hipStream_t stream) {
    const float* x      = (const float*)d_in[0];
    const float* w_init = (const float*)d_in[1];
    const float* b_init = (const float*)d_in[2];
    const float* w_off  = (const float*)d_in[3];
    const float* b_off  = (const float*)d_in[4];
    const float* w_dw   = (const float*)d_in[5];
    const float* b_dw   = (const float*)d_in[6];
    const float* w_pw   = (const float*)d_in[7];
    const float* b_pw   = (const float*)d_in[8];
    float* out = (float*)d_out;

    float*  wt      = (float*)d_ws;
    float*  off_all = wt + (size_t)G_ * 18 * NPOS * CG;
    float*  y       = off_all + (size_t)G_ * NPIX * 18;
    ushort* yb      = (ushort*)(y + (size_t)NPIX * C_);
    ushort* wTh     = yb + (size_t)NPIX * C_;
    ushort* wTl     = wTh + 256 * 256;
    ushort* wpwTh   = wTl + 256 * 256;
    ushort* smp     = wpwTh + (size_t)G_ * KC * CG;

    size_t fixed_bytes = (size_t)((const char*)smp - (const char*)d_ws);
    size_t per_g = (size_t)NPOS * NPIX * CG * sizeof(ushort);   // 42.5 MB
    int ng = 1;
    if      (ws_size >= fixed_bytes + 4 * per_g) ng = 4;
    else if (ws_size >= fixed_bytes + 2 * per_g) ng = 2;

    k_transpose_woff<<<(G_ * 18 * NPOS * CG + 255) / 256, 256, 0, stream>>>(w_off, wt);
    k_cvt_wT_split<<<(256 * 256 + 255) / 256, 256, 0, stream>>>(w_init, wTh, wTl);
    k_cvt_wpwT<<<(G_ * KC * CG + 255) / 256, 256, 0, stream>>>(w_pw, wpwTh);
    k_gemm_init_mfma<<<dim3(NPIX / 64, C_ / 64), 256, 0, stream>>>(x, wTh, wTl,
                                                                   b_init, y, yb);
    k_offconv_all<<<dim3(1024, G_), 256, 0, stream>>>(y, wt, b_off, off_all);

    for (int g0 = 0; g0 < G_; g0 += ng) {
        k_sample<<<dim3(NPOS * NPIX / 16, ng), 256, 0, stream>>>(yb, off_all, smp, g0);
        k_dwpw<<<dim3(576, ng), 256, 0, stream>>>(smp, w_dw, b_dw, wpwTh,
                                                  b_pw, out, g0);
    }
}

// Round 9
// 327.696 us; speedup vs baseline: 1.9269x; 1.5847x over previous
//
#include <hip/hip_runtime.h>
#include <hip/hip_bf16.h>
#include <cstddef>

// Problem constants (B,H,W,C)=(4,96,96,256), G=4, K=3
#define B_   4
#define H_   96
#define W_   96
#define C_   256
#define G_   4
#define CG   64      // C/G
#define NPOS 9       // K*K
#define KC   576     // K*K*CG
#define HW   (H_*W_)      // 9216
#define NPIX (B_*H_*W_)   // 36864

// 2-D pixel tile
#define TM 4
#define TN 16
#define WROWS 6       // TM+2
#define WCOLS 18      // TN+2
#define WPOS  108     // WROWS*WCOLS

typedef float f32x4 __attribute__((ext_vector_type(4)));
typedef float f32x2 __attribute__((ext_vector_type(2)));
typedef short bf16x8 __attribute__((ext_vector_type(8)));

static __device__ __forceinline__ ushort f2bf(float f) {
    unsigned u = __float_as_uint(f);
    unsigned r = (u + 0x7fffu + ((u >> 16) & 1u)) >> 16;   // RNE
    return (ushort)r;
}
static __device__ __forceinline__ float bf2f(ushort u) {
    return __uint_as_float(((unsigned)u) << 16);
}
static __device__ __forceinline__ f32x2 up2(unsigned u) {
    f32x2 f;
    f.x = __uint_as_float(u << 16);
    f.y = __uint_as_float(u & 0xFFFF0000u);
    return f;
}

// ---------------------------------------------------------------------------
// Kc1: w_off [g][3][3][64][18] -> wtT split bf16 [g][oc pad 32][576]
//      (oc 18..31 zeroed). k index = p*64 + c.
// ---------------------------------------------------------------------------
__global__ void k_cvt_woffT(const float* __restrict__ w_off,
                            ushort* __restrict__ wtTh,
                            ushort* __restrict__ wtTl) {
    int idx = blockIdx.x * 256 + threadIdx.x;
    if (idx >= G_ * 32 * KC) return;
    int k  = idx % KC;
    int oc = (idx / KC) & 31;
    int g  = idx / (32 * KC);
    int p = k >> 6, c = k & 63;
    float v = 0.f;
    if (oc < 18) v = w_off[((size_t)(g * NPOS + p) * CG + c) * 18 + oc];
    ushort h = f2bf(v);
    wtTh[idx] = h;
    wtTl[idx] = f2bf(v - bf2f(h));
}

// ---------------------------------------------------------------------------
// Kc2: w_init [k=256][co=256] -> wT split bf16 [co][k]
// ---------------------------------------------------------------------------
__global__ void k_cvt_wT_split(const float* __restrict__ w_init,
                               ushort* __restrict__ wTh,
                               ushort* __restrict__ wTl) {
    int idx = blockIdx.x * 256 + threadIdx.x;
    if (idx >= 256 * 256) return;
    int co = idx & 255, k = idx >> 8;
    float v = w_init[(size_t)k * 256 + co];
    ushort h = f2bf(v);
    wTh[(size_t)co * 256 + k] = h;
    wTl[(size_t)co * 256 + k] = f2bf(v - bf2f(h));
}

// ---------------------------------------------------------------------------
// Kc3: w_pw [g][k=576][f=64] -> wpwT bf16 (hi only) [g][f][k=576]
// ---------------------------------------------------------------------------
__global__ void k_cvt_wpwT(const float* __restrict__ w_pw,
                           ushort* __restrict__ wpwTh) {
    int idx = blockIdx.x * 256 + threadIdx.x;
    if (idx >= G_ * KC * CG) return;
    int f = idx & 63;
    int k = (idx >> 6) % KC;
    int g = idx / (KC * CG);
    wpwTh[((size_t)g * CG + f) * KC + k] = f2bf(w_pw[((size_t)g * KC + k) * CG + f]);
}

// ---------------------------------------------------------------------------
// K1: init 1x1 conv via split-bf16 MFMA (~f32 exact).
// Writes y as split bf16 pair (yh, yl). yh doubles as the bf16 y for the
// sampler's gathers; yh+yl preserve f32 precision for the offsets path.
// ---------------------------------------------------------------------------
__global__ void __launch_bounds__(256) k_gemm_init_mfma(
        const float* __restrict__ x,
        const ushort* __restrict__ wTh, const ushort* __restrict__ wTl,
        const float* __restrict__ bias,
        ushort* __restrict__ yh, ushort* __restrict__ yl) {
    __shared__ __align__(16) ushort ath[64][72], atl[64][72];
    __shared__ __align__(16) ushort bth[64][72], btl[64][72];
    int t = threadIdx.x;
    int px0 = blockIdx.x * 64, n0 = blockIdx.y * 64;
    int r = t >> 2, seg = (t & 3) * 16;
    int lane = t & 63, wv = t >> 6;
    int hl = lane & 15, qv = lane >> 4;
    f32x4 acc[4] = {};
    for (int kk = 0; kk < C_; kk += 64) {
        {
            const float4* xs = (const float4*)(x + (size_t)(px0 + r) * C_ + kk + seg);
            ushort hbuf[16], lbuf[16];
            #pragma unroll
            for (int j = 0; j < 4; j++) {
                float4 v = xs[j];
                float vv[4] = {v.x, v.y, v.z, v.w};
                #pragma unroll
                for (int e2 = 0; e2 < 4; e2++) {
                    ushort h = f2bf(vv[e2]);
                    hbuf[j * 4 + e2] = h;
                    lbuf[j * 4 + e2] = f2bf(vv[e2] - bf2f(h));
                }
            }
            *(uint4*)&ath[r][seg]     = *(uint4*)&hbuf[0];
            *(uint4*)&ath[r][seg + 8] = *(uint4*)&hbuf[8];
            *(uint4*)&atl[r][seg]     = *(uint4*)&lbuf[0];
            *(uint4*)&atl[r][seg + 8] = *(uint4*)&lbuf[8];
        }
        {
            size_t woff = (size_t)(n0 + r) * C_ + kk + seg;
            const uint4* qh = (const uint4*)(wTh + woff);
            const uint4* ql = (const uint4*)(wTl + woff);
            uint4 c0 = qh[0], c1 = qh[1], d0 = ql[0], d1 = ql[1];
            *(uint4*)&bth[r][seg] = c0; *(uint4*)&bth[r][seg + 8] = c1;
            *(uint4*)&btl[r][seg] = d0; *(uint4*)&btl[r][seg + 8] = d1;
        }
        __syncthreads();
        #pragma unroll
        for (int ks = 0; ks < 2; ks++) {
            bf16x8 ah_ = *(const bf16x8*)&ath[wv * 16 + hl][ks * 32 + qv * 8];
            bf16x8 al_ = *(const bf16x8*)&atl[wv * 16 + hl][ks * 32 + qv * 8];
            #pragma unroll
            for (int cg = 0; cg < 4; cg++) {
                bf16x8 bh_ = *(const bf16x8*)&bth[cg * 16 + hl][ks * 32 + qv * 8];
                bf16x8 bl_ = *(const bf16x8*)&btl[cg * 16 + hl][ks * 32 + qv * 8];
                acc[cg] = __builtin_amdgcn_mfma_f32_16x16x32_bf16(ah_, bh_, acc[cg], 0, 0, 0);
                acc[cg] = __builtin_amdgcn_mfma_f32_16x16x32_bf16(ah_, bl_, acc[cg], 0, 0, 0);
                acc[cg] = __builtin_amdgcn_mfma_f32_16x16x32_bf16(al_, bh_, acc[cg], 0, 0, 0);
            }
        }
        __syncthreads();
    }
    #pragma unroll
    for (int cg = 0; cg < 4; cg++) {
        int col = n0 + cg * 16 + hl;
        float bb = bias[col];
        #pragma unroll
        for (int rg = 0; rg < 4; rg++) {
            int row = px0 + wv * 16 + qv * 4 + rg;
            float v = acc[cg][rg] + bb;
            ushort h = f2bf(v);
            yh[(size_t)row * C_ + col] = h;
            yl[(size_t)row * C_ + col] = f2bf(v - bf2f(h));
        }
    }
}

// ---------------------------------------------------------------------------
// K2: offsets 3x3 conv (64 -> 18) via 4-term split-bf16 MFMA (f32-equiv).
// Block = 4x16 pixel tile for group blockIdx.y. The 6x18 y-window (hi/lo)
// is staged ONCE (single barrier); the 9 taps are just shifted ds_reads of
// the same window. B-fragments come straight from L2 (294 KB total).
// ---------------------------------------------------------------------------
__global__ void __launch_bounds__(256) k_offconv_mfma(
        const ushort* __restrict__ yh, const ushort* __restrict__ yl,
        const ushort* __restrict__ wtTh, const ushort* __restrict__ wtTl,
        const float* __restrict__ b_off, float* __restrict__ off_all) {
    __shared__ __align__(16) ushort swh[WPOS][72], swl[WPOS][72];  // 31.1 KB
    int g = blockIdx.y;
    int tile = blockIdx.x;
    int b = tile / 144; int trem = tile - b * 144;
    int r0 = (trem / 6) * TM;
    int c0 = (trem - (trem / 6) * 6) * TN;
    int t = threadIdx.x;
    int lane = t & 63, wv = t >> 6;
    int hl = lane & 15, qv = lane >> 4;
    const int bHW = b * HW;
    // stage window (uint = 2ch): 108 wpos x 32 ch-pairs
    for (int i = t; i < WPOS * 32; i += 256) {
        int w = i >> 5, cq = i & 31;
        int wr = w / WCOLS, wc = w - wr * WCOLS;
        int ny = r0 - 1 + wr, nx = c0 - 1 + wc;
        unsigned vh = 0u, vl = 0u;
        if (((unsigned)ny < (unsigned)H_) && ((unsigned)nx < (unsigned)W_)) {
            size_t base = ((size_t)(bHW + ny * W_ + nx) * C_ + g * CG) >> 1;
            vh = ((const unsigned*)yh)[base + cq];
            vl = ((const unsigned*)yl)[base + cq];
        }
        *(unsigned*)&swh[w][cq * 2] = vh;
        *(unsigned*)&swl[w][cq * 2] = vl;
    }
    __syncthreads();
    f32x4 acc[2] = {};
    const ushort* Wh = wtTh + (size_t)g * 32 * KC;
    const ushort* Wl = wtTl + (size_t)g * 32 * KC;
    for (int p = 0; p < NPOS; p++) {
        int di = p / 3, dj = p - di * 3;
        int wbase = (wv + di) * WCOLS + dj + hl;
        #pragma unroll
        for (int ks = 0; ks < 2; ks++) {
            bf16x8 ah = *(const bf16x8*)&swh[wbase][ks * 32 + qv * 8];
            bf16x8 al = *(const bf16x8*)&swl[wbase][ks * 32 + qv * 8];
            #pragma unroll
            for (int cg = 0; cg < 2; cg++) {
                size_t wo = (size_t)(cg * 16 + hl) * KC + p * 64 + ks * 32 + qv * 8;
                bf16x8 bh = *(const bf16x8*)&Wh[wo];
                bf16x8 bl = *(const bf16x8*)&Wl[wo];
                acc[cg] = __builtin_amdgcn_mfma_f32_16x16x32_bf16(ah, bh, acc[cg], 0, 0, 0);
                acc[cg] = __builtin_amdgcn_mfma_f32_16x16x32_bf16(ah, bl, acc[cg], 0, 0, 0);
                acc[cg] = __builtin_amdgcn_mfma_f32_16x16x32_bf16(al, bh, acc[cg], 0, 0, 0);
                acc[cg] = __builtin_amdgcn_mfma_f32_16x16x32_bf16(al, bl, acc[cg], 0, 0, 0);
            }
        }
    }
    // epilogue: D col = oc = cg*16+hl, D row = pc = qv*4+rg
    #pragma unroll
    for (int cg = 0; cg < 2; cg++) {
        int oc = cg * 16 + hl;
        if (oc < 18) {
            float bo = b_off[g * 18 + oc];
            #pragma unroll
            for (int rg = 0; rg < 4; rg++) {
                int pc = qv * 4 + rg;
                int px = bHW + (r0 + wv) * W_ + (c0 + pc);
                off_all[((size_t)g * NPIX + px) * 18 + oc] = acc[cg][rg] + bo;
            }
        }
    }
}

// ---------------------------------------------------------------------------
// K3: sampling (per pass). Half-wave = one sample, lane = ch-pair -> full
// 256B gather/store transactions. Offsets math f32 == reference.
// ---------------------------------------------------------------------------
__global__ void __launch_bounds__(256) k_sample(
        const ushort* __restrict__ yh, const float* __restrict__ off_all,
        ushort* __restrict__ smp, int g0) {
    int gi = blockIdx.y;
    int g = g0 + gi;
    int t = threadIdx.x;
    int lane = t & 63, wv = t >> 6;
    int hs = lane >> 5;
    int cl = lane & 31;
    int w = blockIdx.x * 4 + wv;
    int s0 = w * 4;
    int p   = s0 / NPIX;
    int px0 = s0 - p * NPIX;
    int di = p / 3, dj = p - di * 3;
    const float* offg = off_all + (size_t)g * NPIX * 18;
    const unsigned* ybu = (const unsigned*)yh;
    unsigned* smpg = (unsigned*)smp + (size_t)gi * NPOS * NPIX * 32;
    #pragma unroll
    for (int q = 0; q < 2; q++) {
        int px = px0 + 2 * q + hs;
        float2 o2 = *(const float2*)&offg[(size_t)px * 18 + 2 * p];
        int b = px / HW; int r2 = px - b * HW;
        int yy = r2 / W_; int xx = r2 - yy * W_;
        float lx = (float)(xx + dj - 1) + o2.x;
        float ly = (float)(yy + di - 1) + o2.y;
        lx = fminf(fmaxf(lx, 0.f), (float)(W_ - 1));
        ly = fminf(fmaxf(ly, 0.f), (float)(H_ - 1));
        float x0f = floorf(lx), y0f = floorf(ly);
        float x1f = fminf(x0f + 1.f, (float)(W_ - 1));
        float y1f = fminf(y0f + 1.f, (float)(H_ - 1));
        float wa = (x1f - lx) * (y1f - ly);
        float wb = (x1f - lx) * (ly - y0f);
        float wc = (lx - x0f) * (y1f - ly);
        float wd = (lx - x0f) * (ly - y0f);
        int ix0 = (int)x0f, iy0 = (int)y0f, ix1 = (int)x1f, iy1 = (int)y1f;
        const unsigned* base = ybu + ((size_t)b * HW) * 128 + g * 32 + cl;
        f32x2 Ia = up2(base[(iy0 * W_ + ix0) * 128]);
        f32x2 Ib = up2(base[(iy1 * W_ + ix0) * 128]);
        f32x2 Ic = up2(base[(iy0 * W_ + ix1) * 128]);
        f32x2 Id = up2(base[(iy1 * W_ + ix1) * 128]);
        f32x2 v = wa * Ia + wb * Ib + wc * Ic + wd * Id;
        unsigned packed = (unsigned)f2bf(v.x) | ((unsigned)f2bf(v.y) << 16);
        smpg[((size_t)p * NPIX + px) * 32 + cl] = packed;
    }
}

// ---------------------------------------------------------------------------
// K4: window-stage + depthwise-3x3 + bf16-MFMA pointwise (per pass).
// ---------------------------------------------------------------------------
__global__ void __launch_bounds__(256, 4) k_dwpw(
        const ushort* __restrict__ smp,
        const float* __restrict__ w_dw, const float* __restrict__ b_dw,
        const ushort* __restrict__ wpwTh, const float* __restrict__ b_pw,
        float* __restrict__ out, int g0) {
    __shared__ __align__(16) ushort swin[WPOS][64];   // 13.5 KB [pos][ch]
    __shared__ __align__(16) ushort ht [64][72];      //  9.0 KB
    __shared__ __align__(16) ushort wt_[64][72];      //  9.0 KB
    int gi = blockIdx.y;
    int g = g0 + gi;
    int tile = blockIdx.x;
    int b = tile / 144; int trem = tile - b * 144;
    int r0 = (trem / 6) * TM;
    int c0 = (trem - (trem / 6) * 6) * TN;
    int t = threadIdx.x;
    int lane = t & 63, wv = t >> 6;
    int hl = lane & 15, qv = lane >> 4;
    int rr = t >> 2, seg = (t & 3) * 16;
    const float* wdwg = w_dw + (size_t)g * NPOS * KC;
    const float* bdwg = b_dw + (size_t)g * KC;
    const ushort* wpwg = wpwTh + (size_t)g * CG * KC;
    const float* bpwg = b_pw + (size_t)g * CG;
    const int bHW = b * HW;
    int cp  = t & 31;
    int pxg = t >> 5;
    int pr  = pxg >> 1;
    int ph  = pxg & 1;

    f32x4 acc[4] = {};
    for (int p = 0; p < NPOS; p++) {
        {
            const uint4* s0 = (const uint4*)(wpwg + (size_t)rr * KC + p * 64 + seg);
            uint4 w0 = s0[0], w1 = s0[1];
            *(uint4*)&wt_[rr][seg]     = w0;
            *(uint4*)&wt_[rr][seg + 8] = w1;
        }
        const ushort* smp_p = smp + (size_t)(gi * NPOS + p) * NPIX * 64;
        #pragma unroll
        for (int k = 0; k < 7; k++) {
            int i = t + k * 256;
            if (i < 1728) {
                int wr  = i / 288;
                int rem = i - wr * 288;
                int pxr = rem >> 4;
                int cq  = rem & 15;
                int ny = r0 - 1 + wr, nx = c0 - 1 + pxr;
                bool inb = ((unsigned)ny < (unsigned)H_) && ((unsigned)nx < (unsigned)W_);
                uint2 v = make_uint2(0u, 0u);
                if (inb)
                    v = *(const uint2*)(smp_p + ((size_t)(bHW + ny * W_ + nx)) * 64 + cq * 4);
                *(uint2*)&swin[wr * WCOLS + pxr][cq * 4] = v;
            }
        }
        __syncthreads();
        {
            f32x2 wd2[9];
            #pragma unroll
            for (int tap = 0; tap < 9; tap++) {
                float2 wv2 = *(const float2*)&wdwg[tap * KC + p * 64 + 2 * cp];
                wd2[tap] = {wv2.x, wv2.y};
            }
            float2 bdv = *(const float2*)&bdwg[p * 64 + 2 * cp];
            int rb0 = (pr + 0) * WCOLS + ph * 8;
            int rb1 = (pr + 1) * WCOLS + ph * 8;
            int rb2 = (pr + 2) * WCOLS + ph * 8;
            #define RD2(pos) up2(*(const unsigned*)&swin[pos][2 * cp])
            f32x2 a0 = RD2(rb0), e0 = RD2(rb0 + 1);
            f32x2 a1 = RD2(rb1), e1 = RD2(rb1 + 1);
            f32x2 a2 = RD2(rb2), e2 = RD2(rb2 + 1);
            #pragma unroll
            for (int c = 0; c < 8; c++) {
                f32x2 c0v = RD2(rb0 + c + 2);
                f32x2 c1v = RD2(rb1 + c + 2);
                f32x2 c2v = RD2(rb2 + c + 2);
                f32x2 hv = {bdv.x, bdv.y};
                hv = hv + a0 * wd2[0] + e0 * wd2[1] + c0v * wd2[2]
                        + a1 * wd2[3] + e1 * wd2[4] + c1v * wd2[5]
                        + a2 * wd2[6] + e2 * wd2[7] + c2v * wd2[8];
                int pxl = pr * 16 + ph * 8 + c;
                unsigned up = (unsigned)f2bf(hv.x) | ((unsigned)f2bf(hv.y) << 16);
                *(unsigned*)&ht[pxl][2 * cp] = up;
                a0 = e0; e0 = c0v; a1 = e1; e1 = c1v; a2 = e2; e2 = c2v;
            }
            #undef RD2
        }
        __syncthreads();
        #pragma unroll
        for (int ks = 0; ks < 2; ks++) {
            bf16x8 a = *(const bf16x8*)&ht[wv * 16 + hl][ks * 32 + qv * 8];
            #pragma unroll
            for (int cg = 0; cg < 4; cg++) {
                bf16x8 bfr = *(const bf16x8*)&wt_[cg * 16 + hl][ks * 32 + qv * 8];
                acc[cg] = __builtin_amdgcn_mfma_f32_16x16x32_bf16(a, bfr, acc[cg], 0, 0, 0);
            }
        }
        __syncthreads();
    }
    #pragma unroll
    for (int cg = 0; cg < 4; cg++) {
        int col = cg * 16 + hl;
        float bb = bpwg[col];
        #pragma unroll
        for (int rg = 0; rg < 4; rg++) {
            int pcol = qv * 4 + rg;
            int px = bHW + (r0 + wv) * W_ + (c0 + pcol);
            out[(size_t)px * C_ + g * CG + col] = acc[cg][rg] + bb;
        }
    }
}

// ---------------------------------------------------------------------------
// ws layout: off_all 10.6MB | yh 18.9MB | yl 18.9MB | wTh/wTl 128KB each |
//            wpwTh 288KB | wtTh/wtTl 144KB each | smp ng*42.5MB
// ---------------------------------------------------------------------------
extern "C" void kernel_launch(void* const* d_in, const int* in_sizes, int n_in,
                              void* d_out, int out_size, void* d_ws, size_t ws_size,
                              hipStream_t stream) {
    const float* x      = (const float*)d_in[0];
    const float* w_init = (const float*)d_in[1];
    const float* b_init = (const float*)d_in[2];
    const float* w_off  = (const float*)d_in[3];
    const float* b_off  = (const float*)d_in[4];
    const float* w_dw   = (const float*)d_in[5];
    const float* b_dw   = (const float*)d_in[6];
    const float* w_pw   = (const float*)d_in[7];
    const float* b_pw   = (const float*)d_in[8];
    float* out = (float*)d_out;

    float*  off_all = (float*)d_ws;
    ushort* yh      = (ushort*)(off_all + (size_t)G_ * NPIX * 18);
    ushort* yl      = yh + (size_t)NPIX * C_;
    ushort* wTh     = yl + (size_t)NPIX * C_;
    ushort* wTl     = wTh + 256 * 256;
    ushort* wpwTh   = wTl + 256 * 256;
    ushort* wtTh    = wpwTh + (size_t)G_ * KC * CG;
    ushort* wtTl    = wtTh + (size_t)G_ * 32 * KC;
    ushort* smp     = wtTl + (size_t)G_ * 32 * KC;

    size_t fixed_bytes = (size_t)((const char*)smp - (const char*)d_ws);
    size_t per_g = (size_t)NPOS * NPIX * CG * sizeof(ushort);   // 42.5 MB
    int ng = 1;
    if      (ws_size >= fixed_bytes + 4 * per_g) ng = 4;
    else if (ws_size >= fixed_bytes + 2 * per_g) ng = 2;

    k_cvt_woffT<<<(G_ * 32 * KC + 255) / 256, 256, 0, stream>>>(w_off, wtTh, wtTl);
    k_cvt_wT_split<<<(256 * 256 + 255) / 256, 256, 0, stream>>>(w_init, wTh, wTl);
    k_cvt_wpwT<<<(G_ * KC * CG + 255) / 256, 256, 0, stream>>>(w_pw, wpwTh);
    k_gemm_init_mfma<<<dim3(NPIX / 64, C_ / 64), 256, 0, stream>>>(x, wTh, wTl,
                                                                   b_init, yh, yl);
    k_offconv_mfma<<<dim3(576, G_), 256, 0, stream>>>(yh, yl, wtTh, wtTl,
                                                      b_off, off_all);

    for (int g0 = 0; g0 < G_; g0 += ng) {
        k_sample<<<dim3(NPOS * NPIX / 16, ng), 256, 0, stream>>>(yh, off_all, smp, g0);
        k_dwpw<<<dim3(576, ng), 256, 0, stream>>>(smp, w_dw, b_dw, wpwTh,
                                                  b_pw, out, g0);
    }
}